// Round 5
// baseline (350.343 us; speedup 1.0000x reference)
//
#include <hip/hip_runtime.h>

// CTC loss forward (reduction='none', zero_infinity=True), matching the JAX ref.
// Shapes: log_probs (T,N,C)=(512,512,80) fp32, targets (N,S)=(512,128) i32.
// Output: (N,) fp32.
//
// R5: one wave per batch element, zero barriers, linear-domain recursion in
// F64 with PER-LANE block exponent E (true alpha = mantissa * 2^E).
//   R4 post-mortem: f32 + E failed at FRONTIER CROSSINGS — empty lanes sit at
//   E=0 while the sender's E decays (losses reach ~2900 bits total); dE
//   clamped at -126 -> aln flushed -> mass never crossed lane boundaries ->
//   all readouts -inf -> all losses zeroed.
//   Fixes: (1) f64 mantissas: 1022-bit window = ~25 sigma vs the ~40-bit-std
//   intra-lane span walk; AMD f64 denormals are IEEE (never flushed).
//   (2) empty lanes INHERIT the left neighbor's E at every rescale (RS=8):
//   frontier moves <=4 lanes/window, inherit chains <=3 windows -> staleness
//   <= ~470 bits << 1022. Alignment is exact: aln = sm1 * 2^(E_{l-1}-E_l),
//   with E static between rescales so alnscale is computed once per rescale.
// Recursion: n[s] = (a[s]+a[s-1]+skip*a[s-2])*p[ext[s]] — f64 add/mul chain;
// 3 f32 exp2/iter (emissions) pipelined 1 row ahead, LDS gathers 2 ahead;
// rows stream via global_load_lds into a 32-deep ring, 1 DMA/iter +
// s_waitcnt vmcnt(29).

#define LOG2E 1.4426950408889634f
#define LN2   0.6931471805599453f

constexpr int T_ = 512;
constexpr int C_ = 80;
constexpr int S_ = 128;
constexpr int D_ = 32;   // ring depth (rows)
constexpr int RS_ = 8;   // rescale interval

// raw s_waitcnt: vmcnt[3:0]|[15:14], expcnt[6:4]=7 (don't care), lgkmcnt[11:8]
#define WAITVM(N) __builtin_amdgcn_s_waitcnt(((N) & 0xF) | ((((N) >> 4) & 3) << 14) | 0x70 | 0xF00)
#define WAIT_LGKM0 __builtin_amdgcn_s_waitcnt(0xC07F)  // lgkmcnt(0)

#define GLD16(gp, sp)                                                        \
    __builtin_amdgcn_global_load_lds(                                        \
        (const __attribute__((address_space(1))) void*)(gp),                 \
        (__attribute__((address_space(3))) void*)(sp), 16, 0, 0)

__device__ __forceinline__ float exp2a(float x) { return __builtin_amdgcn_exp2f(x); }
__device__ __forceinline__ float log2a(float x) { return __builtin_amdgcn_logf(x); }

__device__ __forceinline__ int dpp_shr1_i(int old_, int src) {  // wave_shr:1
    return __builtin_amdgcn_update_dpp(old_, src, 0x138, 0xF, 0xF, false);
}
__device__ __forceinline__ double dpp_shr1_d0(double x) {       // lane0 -> 0.0
    int lo = dpp_shr1_i(0, __double2loint(x));
    int hi = dpp_shr1_i(0, __double2hiint(x));
    return __hiloint2double(hi, lo);
}
__device__ __forceinline__ double pow2d(int k) {                // 2^k, k in [-1022,1023]
    return __hiloint2double((k + 1023) << 20, 0);
}

// log2 of a nonneg f64 as f32 (exponent handled in int; safe for denormals)
__device__ __forceinline__ float flog2d(double a) {
    if (a == 0.0) return -1.0e30f;
    int hi = __double2hiint(a);
    int eb = (hi >> 20) & 0x7FF;
    float extra = 0.f;
    if (eb == 0) {  // denormal: renormalize
        a *= pow2d(512); hi = __double2hiint(a); eb = (hi >> 20) & 0x7FF; extra = -512.f;
    }
    const int lo = __double2loint(a);
    const unsigned fb = 0x3F800000u | (((unsigned)hi & 0xFFFFFu) << 3) | (((unsigned)lo) >> 29);
    return log2a(__uint_as_float(fb)) + (float)(eb - 1023) + extra;
}

__global__ __launch_bounds__(64) void ctc_fwd(
    const float* __restrict__ lp,    // (T,N,C)
    const int*   __restrict__ tgt,   // (N,S)
    const int*   __restrict__ ilen,  // (N)
    const int*   __restrict__ tlen,  // (N)
    float*       __restrict__ out,   // (N)
    int N)
{
    const int n = blockIdx.x;
    const int l = threadIdx.x;       // lane l owns lattice s = 4l..4l+3 (l=63 also 256)

    __shared__ float ring[D_ * C_];  // 32 rows x 80 floats = 10 KB
    __shared__ float af[2 * S_ + 1]; // final alphas, log2 domain

    const int* tn = tgt + n * S_;
    const int ext1 = tn[2 * l];                    // label at s=4l+1
    const int ext3 = tn[2 * l + 1];                // label at s=4l+3
    const int prev = (l > 0) ? tn[2 * l - 1] : 0;
    const bool skip1 = (l > 0) && (ext1 != prev);  // s=1 (l=0): no skip
    const bool skip3 = (ext3 != ext1);

    int len = ilen[n];
    len = len < 1 ? 1 : (len > T_ ? T_ : len);     // alpha frozen for t>=len: stop early

    const float* lpn = lp + (size_t)n * C_;
    const size_t rstride = (size_t)N * C_;
    const bool loader = (l < C_ / 4);              // 20 lanes x 16 B = 320 B/row

    for (int r = 0; r < D_; ++r) {                 // prologue: rows 0..31
        int rc = r < len ? r : (len - 1);
        if (loader) GLD16(lpn + (size_t)rc * rstride + l * 4, &ring[r * C_]);
    }
    WAITVM(D_ - 3);  // rows 0..2 resident

    // t=0: only s=0 and s=1 reachable (linear f64 domain)
    double a0 = 0., a1 = 0., a2 = 0., a3 = 0., a4 = 0.;
    int E = 0;                                     // true = mantissa * 2^E
    if (l == 0) {
        a0 = (double)exp2a(ring[0] * LOG2E);
        a1 = (double)exp2a(ring[ext1] * LOG2E);
    }

    // pipeline primer: probs of row 1 (f64), raw log-probs of row 2 (f32)
    double pb = (double)exp2a(ring[1 * C_ + 0]    * LOG2E);
    double p1 = (double)exp2a(ring[1 * C_ + ext1] * LOG2E);
    double p3 = (double)exp2a(ring[1 * C_ + ext3] * LOG2E);
    float rb  = ring[2 * C_ + 0];
    float rw1 = ring[2 * C_ + ext1];
    float rw3 = ring[2 * C_ + ext3];

    double alnscale = 1.0;   // 2^(E_{l-1} - E_l), exact while E static
    int rs = RS_;

    for (int t = 1; t < len; ++t) {
        {   // exactly one ring DMA per iteration (exact vmcnt<->slot cadence)
            const int rr = t + D_ - 1;
            const int rc = rr < len ? rr : (len - 1);
            if (loader) GLD16(lpn + (size_t)rc * rstride + l * 4,
                              &ring[(rr & (D_ - 1)) * C_]);
        }
        WAITVM(D_ - 3);  // issued = D+t, completed >= t+3 -> rows <= t+2 resident

        // gather raw row t+2 (becomes probs at iter t+2)
        int g = t + 2; if (g > len - 1) g = len - 1;
        const float* rown = &ring[(g & (D_ - 1)) * C_];
        const float nrb = rown[0];
        const float nr1 = rown[ext1];
        const float nr3 = rown[ext3];

        // exp raw row t+1 -> probs for iter t+1 (off the alpha chain)
        const float npb = exp2a(rb  * LOG2E);
        const float np1 = exp2a(rw1 * LOG2E);
        const float np3 = exp2a(rw3 * LOG2E);

        // cross-lane neighbor mantissa, exactly aligned to this lane's E
        const double sm1 = dpp_shr1_d0(a3);        // lane l-1's a3 (lane0 -> 0)
        const double aln = sm1 * alnscale;

        const double z1 = skip1 ? aln : 0.0;       // old[s-2] for s=4l+1 (cross-lane)
        const double z3 = skip3 ? a1  : 0.0;       // old[s-2] for s=4l+3 (same lane)
        const double n0 = (a0 + aln)     * pb;     // s=4l   (blank)
        const double n1 = (a1 + a0 + z1) * p1;     // s=4l+1 (label)
        const double n2 = (a2 + a1)      * pb;     // s=4l+2 (blank)
        const double n3 = (a3 + a2 + z3) * p3;     // s=4l+3 (label)
        const double n4 = (a4 + a3)      * pb;     // s=256 on lane 63 (dup elsewhere)
        a0 = n0; a1 = n1; a2 = n2; a3 = n3; a4 = n4;

        pb = (double)npb; p1 = (double)np1; p3 = (double)np3;
        rb = nrb; rw1 = nr1; rw3 = nr3;

        if (--rs == 0) {   // rescale + empty-lane E inheritance (lane-uniform)
            rs = RS_;
            const double mx = fmax(fmax(a0, a1), fmax(fmax(a2, a3), a4));
            const bool empty = (mx == 0.0);
            const int hi = __double2hiint(mx);
            const int eb = (hi >> 20) & 0x7FF;
            const int e = (eb ? eb : 1) - 1023;    // denorm -> -1022
            const double sc = pow2d(-e < -1022 ? -1022 : (-e > 1023 ? 1023 : -e));
            a0 *= sc; a1 *= sc; a2 *= sc; a3 *= sc; a4 *= sc;  // empty: 0*sc = 0
            const int E1 = empty ? E : (E + e);
            const int Eup1 = dpp_shr1_i(E1, E1);   // left neighbor's fresh E (lane0 -> own)
            E = empty ? Eup1 : E1;
            // refresh exact alignment scale for the next RS iterations
            const int Eup2 = dpp_shr1_i(E, E);
            int dE = Eup2 - E;
            dE = dE < -1022 ? -1022 : (dE > 1023 ? 1023 : dE);
            alnscale = pow2d(dE);
        }
    }

    WAITVM(0);  // drain LDS-DMA before LDS reuse / retire

    // readout in log2 domain: log2(true) = log2(mantissa) + E
    const float Ef = (float)E;
    af[4 * l + 0] = flog2d(a0) + Ef;
    af[4 * l + 1] = flog2d(a1) + Ef;
    af[4 * l + 2] = flog2d(a2) + Ef;
    af[4 * l + 3] = flog2d(a3) + Ef;
    if (l == 63) af[256] = flog2d(a4) + Ef;
    WAIT_LGKM0;  // same-wave LDS writes visible, no barrier needed
    if (l == 0) {
        const int tl = tlen[n];
        const float v1 = af[2 * tl];
        const float v2 = af[2 * tl - 1];
        const float mm = fmaxf(v1, v2);
        float loss = -LN2 * (mm + log2a(exp2a(v1 - mm) + exp2a(v2 - mm)));
        if (!(loss < 1e10f) || !isfinite(loss)) loss = 0.0f;  // zero_infinity
        out[n] = loss;
    }
}

extern "C" void kernel_launch(void* const* d_in, const int* in_sizes, int n_in,
                              void* d_out, int out_size, void* d_ws, size_t ws_size,
                              hipStream_t stream) {
    const float* lp  = (const float*)d_in[0];
    const int*   tg  = (const int*)  d_in[1];
    const int*   il  = (const int*)  d_in[2];
    const int*   tl  = (const int*)  d_in[3];
    float*       out = (float*)d_out;
    const int N = in_sizes[2];  // 512
    ctc_fwd<<<N, 64, 0, stream>>>(lp, tg, il, tl, out, N);
}

// Round 6
// 210.414 us; speedup vs baseline: 1.6650x; 1.6650x over previous
//
#include <hip/hip_runtime.h>

// CTC loss forward (reduction='none', zero_infinity=True), matching the JAX ref.
// Shapes: log_probs (T,N,C)=(512,512,80) fp32, targets (N,S)=(512,128) i32.
// Output: (N,) fp32.
//
// R6 = R2's numerically-verified log2-domain recursion (116 us, absmax 0.0)
// with the two stalls R5 proved removable:
//  (1) emission-row LDS gathers pipelined 2 rows ahead (ds_read -> first use
//      = one full iteration, > ds_read latency), instead of R2's in-iteration
//      gather+use (~150-250 cyc/iter stall);
//  (2) cross-lane a3 via DPP wave_shr:1 with old=NEGC (pure VALU, ~4 cyc)
//      instead of __shfl_up's ds_bpermute (~60-120 cyc LDS-pipe latency on
//      the alpha critical path). DPP 0x138 verified on HW in R5.
// R5 post-mortem: f64 linear-domain chain (fewer transcendentals but longer
// dependent latency) was 2.3x SLOWER — this kernel is chain-latency bound,
// not issue bound; keep the f32 log-domain lse chain.
//
// Structure: one wave per batch element, zero barriers; rows stream via
// global_load_lds into a 32-deep LDS ring, one DMA/iter + s_waitcnt vmcnt(29).

#define NEGC  (-1.0e30f)
#define LOG2E 1.4426950408889634f
#define LN2   0.6931471805599453f

constexpr int T_ = 512;
constexpr int C_ = 80;
constexpr int S_ = 128;
constexpr int D_ = 32;   // ring depth (rows)

// raw s_waitcnt: vmcnt[3:0]|[15:14], expcnt[6:4]=7 (no wait), lgkmcnt[11:8]=15
#define WAITVM(N) __builtin_amdgcn_s_waitcnt(((N) & 0xF) | ((((N) >> 4) & 3) << 14) | 0x70 | 0xF00)
#define WAIT_LGKM0 __builtin_amdgcn_s_waitcnt(0xC07F)  // lgkmcnt(0)

#define GLD16(gp, sp)                                                        \
    __builtin_amdgcn_global_load_lds(                                        \
        (const __attribute__((address_space(1))) void*)(gp),                 \
        (__attribute__((address_space(3))) void*)(sp), 16, 0, 0)

__device__ __forceinline__ float exp2a(float x) { return __builtin_amdgcn_exp2f(x); }
__device__ __forceinline__ float log2a(float x) { return __builtin_amdgcn_logf(x); }

template <int CTRL>
__device__ __forceinline__ float dppf(float old_, float src) {
    return __int_as_float(__builtin_amdgcn_update_dpp(
        __float_as_int(old_), __float_as_int(src), CTRL, 0xF, 0xF, false));
}

// log-sum-exp, base-2 domain
__device__ __forceinline__ float lse2(float x, float y) {
    float m = fmaxf(x, y);
    return m + log2a(1.0f + exp2a(-fabsf(x - y)));
}
__device__ __forceinline__ float lse3(float x, float y, float z) {
    float m = fmaxf(x, fmaxf(y, z));
    return m + log2a(exp2a(x - m) + exp2a(y - m) + exp2a(z - m));
}

__global__ __launch_bounds__(64) void ctc_fwd(
    const float* __restrict__ lp,    // (T,N,C)
    const int*   __restrict__ tgt,   // (N,S)
    const int*   __restrict__ ilen,  // (N)
    const int*   __restrict__ tlen,  // (N)
    float*       __restrict__ out,   // (N)
    int N)
{
    const int n = blockIdx.x;
    const int l = threadIdx.x;       // lane l owns lattice s=4l..4l+3 (l=63 also 256)

    __shared__ float ring[D_ * C_];  // 32 rows x 80 floats = 10 KB
    __shared__ float af[2 * S_ + 1]; // final alphas (log2 domain)

    const int* tn = tgt + n * S_;
    const int ext1 = tn[2 * l];                    // label at s=4l+1
    const int ext3 = tn[2 * l + 1];                // label at s=4l+3
    const int prev = (l > 0) ? tn[2 * l - 1] : 0;
    const bool skip1 = (l > 0) && (ext1 != prev);  // s=1 (l=0): no skip
    const bool skip3 = (ext3 != ext1);

    int len = ilen[n];
    len = len < 1 ? 1 : (len > T_ ? T_ : len);     // alpha frozen for t>=len: stop early

    const float* lpn = lp + (size_t)n * C_;
    const size_t rstride = (size_t)N * C_;
    const bool loader = (l < C_ / 4);              // 20 lanes x 16 B = 320 B/row

    for (int r = 0; r < D_; ++r) {                 // prologue: rows 0..31
        int rc = r < len ? r : (len - 1);
        if (loader) GLD16(lpn + (size_t)rc * rstride + l * 4, &ring[r * C_]);
    }
    WAITVM(D_ - 3);  // rows 0..2 resident

    // t=0 (log2 domain): only s=0 and s=1 reachable
    float a0 = NEGC, a1 = NEGC, a2 = NEGC, a3 = NEGC, a4 = NEGC;
    if (l == 0) {
        a0 = ring[0] * LOG2E;
        a1 = ring[ext1] * LOG2E;
    }

    // pipeline primer: emissions of row 1 (converted), raw of row 2
    float eb = ring[1 * C_ + 0]    * LOG2E;
    float e1 = ring[1 * C_ + ext1] * LOG2E;
    float e3 = ring[1 * C_ + ext3] * LOG2E;
    float rb  = ring[2 * C_ + 0];
    float rw1 = ring[2 * C_ + ext1];
    float rw3 = ring[2 * C_ + ext3];

    for (int t = 1; t < len; ++t) {
        {   // exactly one ring DMA per iteration (exact vmcnt<->slot cadence)
            const int rr = t + D_ - 1;
            const int rc = rr < len ? rr : (len - 1);
            if (loader) GLD16(lpn + (size_t)rc * rstride + l * 4,
                              &ring[(rr & (D_ - 1)) * C_]);
        }
        WAITVM(D_ - 3);  // issued = D+t, completed >= t+3 -> rows <= t+2 resident

        // gather raw row t+2 (first used next iteration -> full-iter slack)
        int g = t + 2; if (g > len - 1) g = len - 1;
        const float* rown = &ring[(g & (D_ - 1)) * C_];
        const float nrb = rown[0];
        const float nr1 = rown[ext1];
        const float nr3 = rown[ext3];

        // convert raw row t+1 -> emissions for iter t+1 (3 muls, off chain)
        const float neb = rb  * LOG2E;
        const float ne1 = rw1 * LOG2E;
        const float ne3 = rw3 * LOG2E;

        // cross-lane old alpha at s=4l-1 via DPP (lane 0 -> NEGC)
        const float sm1 = dppf<0x138>(NEGC, a3);   // wave_shr:1

        const float z1 = skip1 ? sm1 : NEGC;       // old[s-2] for s=4l+1
        const float z3 = skip3 ? a1  : NEGC;       // old[s-2] for s=4l+3

        const float n0 = lse2(a0, sm1)    + eb;    // s=4l   (blank)
        const float n1 = lse3(a1, a0, z1) + e1;    // s=4l+1 (label)
        const float n2 = lse2(a2, a1)     + eb;    // s=4l+2 (blank)
        const float n3 = lse3(a3, a2, z3) + e3;    // s=4l+3 (label)
        const float n4 = lse2(a4, a3)     + eb;    // s=256 on lane 63 (unused elsewhere)
        a0 = n0; a1 = n1; a2 = n2; a3 = n3; a4 = n4;

        eb = neb; e1 = ne1; e3 = ne3;
        rb = nrb; rw1 = nr1; rw3 = nr3;
    }

    WAITVM(0);  // drain LDS-DMA before retire

    // readout: final states s=2*tl (last blank), s=2*tl-1 (last label)
    af[4 * l + 0] = a0; af[4 * l + 1] = a1;
    af[4 * l + 2] = a2; af[4 * l + 3] = a3;
    if (l == 63) af[256] = a4;
    WAIT_LGKM0;  // same-wave LDS writes visible, no barrier needed
    if (l == 0) {
        const int tl = tlen[n];
        const float v1 = af[2 * tl];
        const float v2 = af[2 * tl - 1];
        float loss = -lse2(v1, v2) * LN2;
        if (!(loss < 1e10f) || !isfinite(loss)) loss = 0.0f;  // zero_infinity
        out[n] = loss;
    }
}

extern "C" void kernel_launch(void* const* d_in, const int* in_sizes, int n_in,
                              void* d_out, int out_size, void* d_ws, size_t ws_size,
                              hipStream_t stream) {
    const float* lp  = (const float*)d_in[0];
    const int*   tg  = (const int*)  d_in[1];
    const int*   il  = (const int*)  d_in[2];
    const int*   tl  = (const int*)  d_in[3];
    float*       out = (float*)d_out;
    const int N = in_sizes[2];  // 512
    ctc_fwd<<<N, 64, 0, stream>>>(lp, tg, il, tl, out, N);
}

// Round 7
// 202.811 us; speedup vs baseline: 1.7274x; 1.0375x over previous
//
#include <hip/hip_runtime.h>

// CTC loss forward (reduction='none', zero_infinity=True), matching the JAX ref.
// Shapes: log_probs (T,N,C)=(512,512,80) fp32, targets (N,S)=(512,128) i32.
// Output: (N,) fp32.
//
// R7: one wave per batch element, and the loop touches NO LDS AT ALL.
//   R6 post-mortem: removing ds_bpermute + in-iter gathers changed nothing
//   (116 -> 113 us): the ~320 idle cyc/iter is the in-loop LDS/DMA machinery
//   (global_load_lds + raw vmcnt + ds_read gathers forcing conservative
//   lgkmcnt waits), not the consumers I moved. So: remove it wholesale.
//   Each lane only needs 3 floats/row (blank, ext1, ext3 emissions) -> load
//   them straight to VGPRs through an 8-deep register ring (unroll 8,
//   compile-time slots; use-distance = 8 iters ~ 4000 cyc >> HBM latency).
//   No manual waitcnt: the compiler tracks VGPR loads precisely and emits
//   fine-grained vmcnt. Alpha recursion = R2/R6's verified log2-domain LSE;
//   cross-lane via DPP wave_shr:1 (VALU-only).

#define NEGC  (-1.0e30f)
#define LOG2E 1.4426950408889634f
#define LN2   0.6931471805599453f

constexpr int T_ = 512;
constexpr int C_ = 80;
constexpr int S_ = 128;
constexpr int U_ = 8;    // register-ring depth / unroll factor

#define WAIT_LGKM0 __builtin_amdgcn_s_waitcnt(0xC07F)  // lgkmcnt(0)

__device__ __forceinline__ float exp2a(float x) { return __builtin_amdgcn_exp2f(x); }
__device__ __forceinline__ float log2a(float x) { return __builtin_amdgcn_logf(x); }

template <int CTRL>
__device__ __forceinline__ float dppf(float old_, float src) {
    return __int_as_float(__builtin_amdgcn_update_dpp(
        __float_as_int(old_), __float_as_int(src), CTRL, 0xF, 0xF, false));
}

// log-sum-exp, base-2 domain (verified in R2/R6)
__device__ __forceinline__ float lse2(float x, float y) {
    float m = fmaxf(x, y);
    return m + log2a(1.0f + exp2a(-fabsf(x - y)));
}
__device__ __forceinline__ float lse3(float x, float y, float z) {
    float m = fmaxf(x, fmaxf(y, z));
    return m + log2a(exp2a(x - m) + exp2a(y - m) + exp2a(z - m));
}

__global__ __launch_bounds__(64) void ctc_fwd(
    const float* __restrict__ lp,    // (T,N,C)
    const int*   __restrict__ tgt,   // (N,S)
    const int*   __restrict__ ilen,  // (N)
    const int*   __restrict__ tlen,  // (N)
    float*       __restrict__ out,   // (N)
    int N)
{
    const int n = blockIdx.x;
    const int l = threadIdx.x;       // lane l owns lattice s=4l..4l+3 (l=63 also 256)

    __shared__ float af[2 * S_ + 1]; // final-alpha readout only (not in loop)

    const int* tn = tgt + n * S_;
    const int ext1 = tn[2 * l];                    // label at s=4l+1
    const int ext3 = tn[2 * l + 1];                // label at s=4l+3
    const int prev = (l > 0) ? tn[2 * l - 1] : 0;
    const bool skip1 = (l > 0) && (ext1 != prev);  // s=1 (l=0): no skip
    const bool skip3 = (ext3 != ext1);

    int len = ilen[n];
    len = len < 1 ? 1 : (len > T_ ? T_ : len);     // alpha frozen for t>=len: stop early

    const size_t rstride = (size_t)N * C_;         // floats per timestep
    const float* lpn = lp + (size_t)n * C_;
    const float* pB = lpn;                         // blank   (lane-uniform value)
    const float* p1 = lpn + ext1;                  // label at s=4l+1 (per-lane)
    const float* p3 = lpn + ext3;                  // label at s=4l+3 (per-lane)

    // register ring: raw log-probs for rows t, slot = t & 7
    float rb[U_], r1[U_], r3[U_];
    #pragma unroll
    for (int u = 0; u < U_; ++u) {
        const int r = u + 1;                       // rows 1..8 -> slots 1..7,0
        const int rc = r < len ? r : len - 1;
        const size_t o = (size_t)rc * rstride;
        rb[r & 7] = pB[o]; r1[r & 7] = p1[o]; r3[r & 7] = p3[o];
    }

    // t=0 init (row 0 direct): only s=0 and s=1 reachable
    float a0 = NEGC, a1 = NEGC, a2 = NEGC, a3 = NEGC, a4 = NEGC;
    {
        const float i0 = pB[0] * LOG2E;
        const float i1 = p1[0] * LOG2E;
        if (l == 0) { a0 = i0; a1 = i1; }
    }

    for (int tb = 1; tb < len; tb += U_) {
        #pragma unroll
        for (int u = 0; u < U_; ++u) {
            const int t = tb + u;
            const int slot = (1 + u) & 7;          // == t&7 (tb ≡ 1 mod 8): compile-time

            // emissions for row t (loaded 8 iterations ago)
            const float eb = rb[slot] * LOG2E;
            const float e1 = r1[slot] * LOG2E;
            const float e3 = r3[slot] * LOG2E;

            // refill slot with row t+8 (clamped); in flight for 8 iterations
            const int rr = t + U_;
            const int rc = rr < len ? rr : len - 1;
            const size_t o = (size_t)rc * rstride;
            const float nrb = pB[o];
            const float nr1 = p1[o];
            const float nr3 = p3[o];

            if (t < len) {                          // wave-uniform guard (pad iters skip)
                const float sm1 = dppf<0x138>(NEGC, a3);   // lane l-1's a3 (lane0 -> NEGC)
                const float z1 = skip1 ? sm1 : NEGC;       // old[s-2] for s=4l+1
                const float z3 = skip3 ? a1  : NEGC;       // old[s-2] for s=4l+3

                const float n0 = lse2(a0, sm1)    + eb;    // s=4l   (blank)
                const float n1 = lse3(a1, a0, z1) + e1;    // s=4l+1 (label)
                const float n2 = lse2(a2, a1)     + eb;    // s=4l+2 (blank)
                const float n3 = lse3(a3, a2, z3) + e3;    // s=4l+3 (label)
                const float n4 = lse2(a4, a3)     + eb;    // s=256 (lane 63; unused elsewhere)
                a0 = n0; a1 = n1; a2 = n2; a3 = n3; a4 = n4;
            }

            rb[slot] = nrb; r1[slot] = nr1; r3[slot] = nr3;
        }
    }

    // readout: final states s=2*tl (last blank), s=2*tl-1 (last label)
    af[4 * l + 0] = a0; af[4 * l + 1] = a1;
    af[4 * l + 2] = a2; af[4 * l + 3] = a3;
    if (l == 63) af[256] = a4;
    WAIT_LGKM0;  // same-wave LDS writes visible; single wave -> no barrier
    if (l == 0) {
        const int tl = tlen[n];
        const float v1 = af[2 * tl];
        const float v2 = af[2 * tl - 1];
        float loss = -lse2(v1, v2) * LN2;
        if (!(loss < 1e10f) || !isfinite(loss)) loss = 0.0f;  // zero_infinity
        out[n] = loss;
    }
}

extern "C" void kernel_launch(void* const* d_in, const int* in_sizes, int n_in,
                              void* d_out, int out_size, void* d_ws, size_t ws_size,
                              hipStream_t stream) {
    const float* lp  = (const float*)d_in[0];
    const int*   tg  = (const int*)  d_in[1];
    const int*   il  = (const int*)  d_in[2];
    const int*   tl  = (const int*)  d_in[3];
    float*       out = (float*)d_out;
    const int N = in_sizes[2];  // 512
    ctc_fwd<<<N, 64, 0, stream>>>(lp, tg, il, tl, out, N);
}

// Round 8
// 173.807 us; speedup vs baseline: 2.0157x; 1.1669x over previous
//
#include <hip/hip_runtime.h>

// CTC loss forward (reduction='none', zero_infinity=True), matching the JAX ref.
// Shapes: log_probs (T,N,C)=(512,512,80) fp32, targets (N,S)=(512,128) i32.
// Output: (N,) fp32.
//
// R8: FORWARD/BACKWARD MIDPOINT SPLIT. R7 post-mortem: with all memory paths
// eliminated (bank conflicts 0), time is invariant ~110 us => bound by the
// serial per-iteration chain x 511 steps at 0.5 waves/SIMD. So halve the
// chain and double the waves: per batch element, wave 0 computes alpha
// forward over frames 0..mid-1, wave 1 computes gamma (suffix) backward over
// frames len-1..mid, concurrently. P = sum_s' abar[s'] * gamma_mid[s'],
//   abar[s'] = lse(alpha[s'], alpha[s'-1], skip_ok[s']*alpha[s'-2])
//   gamma_t[s] = emit_t[s] + lse(g[s], g[s+1], skip_ok[s+2]*g[s+2])
// (verified by path enumeration at T=2,3). One __syncthreads total, then a
// one-time 257-term lse dot product.
// Loops keep R7's LDS-free register-ring streaming (8-deep, 3 floats/lane).
// Cross-lane: fwd DPP wave_shr:1 (0x138, HW-verified = shfl_up); bwd DPP
// wave_shl:1 (0x130 = shfl_down), old operand supplies lane 63's boundary.

#define NEGC  (-1.0e30f)
#define LOG2E 1.4426950408889634f
#define LN2   0.6931471805599453f

constexpr int T_ = 512;
constexpr int C_ = 80;
constexpr int S_ = 128;
constexpr int U_ = 8;    // register-ring depth / unroll

#define WAIT_LGKM0 __builtin_amdgcn_s_waitcnt(0xC07F)

__device__ __forceinline__ float exp2a(float x) { return __builtin_amdgcn_exp2f(x); }
__device__ __forceinline__ float log2a(float x) { return __builtin_amdgcn_logf(x); }

template <int CTRL>
__device__ __forceinline__ float dppf(float old_, float src) {
    return __int_as_float(__builtin_amdgcn_update_dpp(
        __float_as_int(old_), __float_as_int(src), CTRL, 0xF, 0xF, false));
}

// log-sum-exp, base-2 domain (verified R2/R6/R7)
__device__ __forceinline__ float lse2(float x, float y) {
    float m = fmaxf(x, y);
    return m + log2a(1.0f + exp2a(-fabsf(x - y)));
}
__device__ __forceinline__ float lse3(float x, float y, float z) {
    float m = fmaxf(x, fmaxf(y, z));
    return m + log2a(exp2a(x - m) + exp2a(y - m) + exp2a(z - m));
}

__global__ __launch_bounds__(128) void ctc_fwd(
    const float* __restrict__ lp,    // (T,N,C)
    const int*   __restrict__ tgt,   // (N,S)
    const int*   __restrict__ ilen,  // (N)
    const int*   __restrict__ tlen,  // (N)
    float*       __restrict__ out,   // (N)
    int N)
{
    const int n    = blockIdx.x;
    const int wave = threadIdx.x >> 6;   // 0 = forward, 1 = backward
    const int l    = threadIdx.x & 63;   // lane: owns lattice s=4l..4l+3 (l=63 also 256)

    __shared__ float ga[2 * S_ + 1];     // alpha_{mid-1} (log2)
    __shared__ float gg[2 * S_ + 1];     // gamma_mid (log2)

    const int* tn = tgt + n * S_;
    const int ext1 = tn[2 * l];                     // label at s=4l+1
    const int ext3 = tn[2 * l + 1];                 // label at s=4l+3
    const int prev = (l > 0) ? tn[2 * l - 1] : 0;
    const bool skip1 = (l > 0) && (ext1 != prev);   // skip_ok[4l+1]
    const bool skip3 = (ext3 != ext1);              // skip_ok[4l+3]
    // backward skip flags: skip_ok[s+2] for s=4l+1 / 4l+3
    const bool skb1 = (tn[2 * l + 1] != tn[2 * l]);                   // skip_ok[4l+3]
    const bool skb3 = (l < 63) && (tn[2 * l + 2] != tn[2 * l + 1]);   // skip_ok[4l+5]

    int len = ilen[n];
    len = len < 1 ? 1 : (len > T_ ? T_ : len);
    const int mid = len >> 1;            // fwd: frames 0..mid-1; bwd: mid..len-1

    const size_t rstride = (size_t)N * C_;
    const float* lpn = lp + (size_t)n * C_;
    const float* pB = lpn;               // blank emission stream
    const float* p1 = lpn + ext1;
    const float* p3 = lpn + ext3;

    float rb[U_], r1[U_], r3[U_];        // register ring (raw log-probs)

    if (wave == 0) {
        // ---------------- forward: alpha_{mid-1} ----------------
        const int last = mid - 1 > 0 ? mid - 1 : 0;
        #pragma unroll
        for (int u = 0; u < U_; ++u) {   // preload rows 1..8 (clamped)
            const int r = u + 1;
            const int rc = r < mid ? r : last;
            const size_t o = (size_t)rc * rstride;
            rb[r & 7] = pB[o]; r1[r & 7] = p1[o]; r3[r & 7] = p3[o];
        }
        float a0 = NEGC, a1 = NEGC, a2 = NEGC, a3 = NEGC, a4 = NEGC;
        {
            const float i0 = pB[0] * LOG2E;
            const float i1 = p1[0] * LOG2E;
            if (l == 0) { a0 = i0; a1 = i1; }
        }
        for (int tb = 1; tb < mid; tb += U_) {
            #pragma unroll
            for (int u = 0; u < U_; ++u) {
                const int t = tb + u;
                const int slot = (1 + u) & 7;              // == t&7
                const float eb = rb[slot] * LOG2E;
                const float e1 = r1[slot] * LOG2E;
                const float e3 = r3[slot] * LOG2E;
                const int rr = t + U_;
                const int rc = rr < mid ? rr : last;
                const size_t o = (size_t)rc * rstride;
                const float nrb = pB[o], nr1 = p1[o], nr3 = p3[o];
                if (t < mid) {
                    const float sm1 = dppf<0x138>(NEGC, a3);   // lane l-1's a3
                    const float z1 = skip1 ? sm1 : NEGC;
                    const float z3 = skip3 ? a1  : NEGC;
                    const float n0 = lse2(a0, sm1)    + eb;
                    const float n1 = lse3(a1, a0, z1) + e1;
                    const float n2 = lse2(a2, a1)     + eb;
                    const float n3 = lse3(a3, a2, z3) + e3;
                    const float n4 = lse2(a4, a3)     + eb;    // s=256 (lane 63)
                    a0 = n0; a1 = n1; a2 = n2; a3 = n3; a4 = n4;
                }
                rb[slot] = nrb; r1[slot] = nr1; r3[slot] = nr3;
            }
        }
        ga[4 * l + 0] = a0; ga[4 * l + 1] = a1;
        ga[4 * l + 2] = a2; ga[4 * l + 3] = a3;
        if (l == 63) ga[256] = a4;
    } else {
        // ---------------- backward: gamma_mid ----------------
        const int fe = len - 1;          // init frame
        #pragma unroll
        for (int u = 0; u < U_; ++u) {   // preload rows fe-1-u (clamped >= 0)
            int rc = fe - 1 - u; if (rc < 0) rc = 0;
            const size_t o = (size_t)rc * rstride;
            rb[u] = pB[o]; r1[u] = p1[o]; r3[u] = p3[o];
        }
        // init: gamma_{fe}[s] = emit_fe[s] if s in {2tl, 2tl-1} else NEG
        const int tl = tlen[n];
        const int sA = 2 * tl, sB = 2 * tl - 1;
        float g0, g1, g2, g3, g4;
        {
            const size_t o = (size_t)fe * rstride;
            const float ebi = pB[o] * LOG2E;
            const float e1i = p1[o] * LOG2E;
            const float e3i = p3[o] * LOG2E;
            const int s0 = 4 * l;
            g0 = (s0     == sA)               ? ebi : NEGC;   // even: blank
            g1 = (s0 + 1 == sA || s0 + 1 == sB) ? e1i : NEGC;
            g2 = (s0 + 2 == sA)               ? ebi : NEGC;
            g3 = (s0 + 3 == sA || s0 + 3 == sB) ? e3i : NEGC;
            g4 = (l == 63 && 256 == sA)       ? ebi : NEGC;
        }
        for (int tb = fe - 1; tb >= mid; tb -= U_) {
            #pragma unroll
            for (int u = 0; u < U_; ++u) {
                const int t = tb - u;
                const int slot = ((fe - 1 - tb) + u) & 7;  // == u (fe-1-tb ≡ 0 mod 8)
                const float eb = rb[slot] * LOG2E;
                const float e1 = r1[slot] * LOG2E;
                const float e3 = r3[slot] * LOG2E;
                int rc = t - U_; if (rc < 0) rc = 0;
                const size_t o = (size_t)rc * rstride;
                const float nrb = pB[o], nr1 = p1[o], nr3 = p3[o];
                if (t >= mid) {
                    const float nx0 = dppf<0x130>(g4,   g0);   // lane l+1's g0; l=63 -> own g4 (s=256)
                    const float nx1 = dppf<0x130>(NEGC, g1);   // lane l+1's g1; l=63 -> NEG (s=257)
                    const float z1 = skb1 ? g3  : NEGC;        // skip_ok[4l+3]
                    const float z3 = skb3 ? nx1 : NEGC;        // skip_ok[4l+5]
                    const float n0 = lse2(g0, g1)      + eb;   // s=4l (even: no skip out)
                    const float n1 = lse3(g1, g2, z1)  + e1;   // s=4l+1
                    const float n2 = lse2(g2, g3)      + eb;   // s=4l+2
                    const float n3 = lse3(g3, nx0, z3) + e3;   // s=4l+3
                    const float n4 = g4 + eb;                  // s=256: stay only
                    g0 = n0; g1 = n1; g2 = n2; g3 = n3; g4 = n4;
                }
                rb[slot] = nrb; r1[slot] = nr1; r3[slot] = nr3;
            }
        }
        gg[4 * l + 0] = g0; gg[4 * l + 1] = g1;
        gg[4 * l + 2] = g2; gg[4 * l + 3] = g3;
        if (l == 63) gg[256] = g4;
    }

    __syncthreads();   // once per kernel; drains ring loads, publishes ga/gg

    if (wave == 0) {
        const int tl = tlen[n];
        if (len == 1) {            // degenerate: loss directly from alpha_0
            if (l == 0) {
                const float v1 = ga[2 * tl];
                const float v2 = (2 * tl >= 1) ? ga[2 * tl - 1] : NEGC;
                float loss = -lse2(v1, v2) * LN2;
                if (!(loss < 1e10f) || !isfinite(loss)) loss = 0.0f;
                out[n] = loss;
            }
            return;
        }
        // v[s] = abar[s] + gamma_mid[s];  abar[s] = lse(A[s], A[s-1], skip_ok[s]*A[s-2])
        const int s0 = 4 * l;
        const float Am1 = (l > 0) ? ga[s0 - 1] : NEGC;   // A[4l-1]
        const float A0 = ga[s0], A1 = ga[s0 + 1], A2 = ga[s0 + 2], A3 = ga[s0 + 3];
        const float v0 = lse2(A0, Am1)                      + gg[s0];
        const float v1 = lse3(A1, A0, skip1 ? Am1 : NEGC)   + gg[s0 + 1];
        const float v2 = lse2(A2, A1)                       + gg[s0 + 2];
        const float v3 = lse3(A3, A2, skip3 ? A1 : NEGC)    + gg[s0 + 3];
        const float v4 = (l == 63) ? (lse2(ga[256], A3) + gg[256]) : NEGC;

        // lane-local lse, then 64-lane butterfly lse-reduction
        float m = fmaxf(fmaxf(v0, v1), fmaxf(fmaxf(v2, v3), v4));
        float ssum = exp2a(v0 - m) + exp2a(v1 - m) + exp2a(v2 - m)
                   + exp2a(v3 - m) + exp2a(v4 - m);          // all-NEG lane: m=NEG, harmless
        float M = m;
        #pragma unroll
        for (int d = 1; d < 64; d <<= 1) M = fmaxf(M, __shfl_xor(M, d));
        float r = ssum * exp2a(m - M);                        // NEG lanes -> 0
        #pragma unroll
        for (int d = 1; d < 64; d <<= 1) r += __shfl_xor(r, d);
        if (l == 0) {
            float loss = -LN2 * (M + log2a(r));
            if (!(loss < 1e10f) || !isfinite(loss)) loss = 0.0f;  // zero_infinity
            out[n] = loss;
        }
    }
}

extern "C" void kernel_launch(void* const* d_in, const int* in_sizes, int n_in,
                              void* d_out, int out_size, void* d_ws, size_t ws_size,
                              hipStream_t stream) {
    const float* lp  = (const float*)d_in[0];
    const int*   tg  = (const int*)  d_in[1];
    const int*   il  = (const int*)  d_in[2];
    const int*   tl  = (const int*)  d_in[3];
    float*       out = (float*)d_out;
    const int N = in_sizes[2];  // 512
    ctc_fwd<<<N, 128, 0, stream>>>(lp, tg, il, tl, out, N);
}

// Round 9
// 156.597 us; speedup vs baseline: 2.2372x; 1.1099x over previous
//
#include <hip/hip_runtime.h>

// CTC loss forward (reduction='none', zero_infinity=True), matching the JAX ref.
// Shapes: log_probs (T,N,C)=(512,512,80) fp32, targets (N,S)=(512,128) i32.
// Output: (N,) fp32.
//
// R9: (a) SHARED-MAX LSE: one per-lane max M over all lse operands (<=6
// adjacent lattice positions), burst of independent exp2's, burst of
// independent log2's. 14->11 trans/iter fwd, 12->10 bwd, and the serial
// chain collapses from five internally-serial lse's to
// fmax-tree->sub->exp2->add->log2->add. Accuracy: a term flushes only when
// >=126 bits below an adjacent position's alpha (ref's own f32 lse drops at
// 2^-24) — contributes <=2^-126 relative mass, negligible.
// (b) SIMD DE-CONTENTION: R8 post-mortem showed per-iter 507->743 cyc when
// fwd+bwd waves shared a workgroup (trans-pipe contention on one SIMD). Now
// fwd and bwd are SEPARATE 64-thread blocks (grid 2N) writing alpha_mid /
// gamma_mid to d_ws; a tiny second kernel combines. 1024 independent
// workgroups spread ~1/SIMD. Fallback to the proven fused R8 kernel if
// ws_size is too small (host-side constant branch: graph-safe).

#define NEGC  (-1.0e30f)
#define LOG2E 1.4426950408889634f
#define LN2   0.6931471805599453f

constexpr int T_ = 512;
constexpr int C_ = 80;
constexpr int S_ = 128;
constexpr int U_ = 8;        // register-ring depth / unroll
constexpr int WROW = 520;    // ws floats per n: ga @0 (257), gg @260 (257)

__device__ __forceinline__ float exp2a(float x) { return __builtin_amdgcn_exp2f(x); }
__device__ __forceinline__ float log2a(float x) { return __builtin_amdgcn_logf(x); }

template <int CTRL>
__device__ __forceinline__ float dppf(float old_, float src) {
    return __int_as_float(__builtin_amdgcn_update_dpp(
        __float_as_int(old_), __float_as_int(src), CTRL, 0xF, 0xF, false));
}

// classic lse (combine/fallback only)
__device__ __forceinline__ float lse2(float x, float y) {
    float m = fmaxf(x, y);
    return m + log2a(1.0f + exp2a(-fabsf(x - y)));
}
__device__ __forceinline__ float lse3(float x, float y, float z) {
    float m = fmaxf(x, fmaxf(y, z));
    return m + log2a(exp2a(x - m) + exp2a(y - m) + exp2a(z - m));
}

// ---------------- main: one 64-thread block per (n, direction) ----------------
__global__ __launch_bounds__(64) void ctc_half(
    const float* __restrict__ lp, const int* __restrict__ tgt,
    const int* __restrict__ ilen, const int* __restrict__ tlen,
    float* __restrict__ ws, int N)
{
    const int b   = blockIdx.x;
    const int n   = b >> 1;
    const int dir = b & 1;               // 0 = forward, 1 = backward
    const int l   = threadIdx.x;         // lane l owns lattice s=4l..4l+3 (l=63 also 256)

    float* ga = ws + (size_t)n * WROW;        // alpha_{mid-1} (log2)
    float* gg = ga + 260;                     // gamma_mid (log2)

    const int* tn = tgt + n * S_;
    const int ext1 = tn[2 * l];
    const int ext3 = tn[2 * l + 1];
    const int prev = (l > 0) ? tn[2 * l - 1] : 0;
    const bool skip1 = (l > 0) && (ext1 != prev);                     // skip_ok[4l+1]
    const bool skip3 = (ext3 != ext1);                                // skip_ok[4l+3]
    const bool skb3  = (l < 63) && (tn[2 * l + 2] != ext3);           // skip_ok[4l+5]

    int len = ilen[n];
    len = len < 1 ? 1 : (len > T_ ? T_ : len);
    const int mid = len >> 1;            // fwd frames 0..mid-1; bwd frames mid..len-1

    const size_t rstride = (size_t)N * C_;
    const float* lpn = lp + (size_t)n * C_;
    const float* pB = lpn;
    const float* p1 = lpn + ext1;
    const float* p3 = lpn + ext3;

    float rb[U_], r1[U_], r3[U_];

    if (dir == 0) {
        // ---------------- forward: alpha_{mid-1} ----------------
        const int last = mid - 1 > 0 ? mid - 1 : 0;
        #pragma unroll
        for (int u = 0; u < U_; ++u) {
            const int r = u + 1;
            const int rc = r < mid ? r : last;
            const size_t o = (size_t)rc * rstride;
            rb[r & 7] = pB[o]; r1[r & 7] = p1[o]; r3[r & 7] = p3[o];
        }
        float a0 = NEGC, a1 = NEGC, a2 = NEGC, a3 = NEGC, a4 = NEGC;
        {
            const float i0 = pB[0] * LOG2E;
            const float i1 = p1[0] * LOG2E;
            if (l == 0) { a0 = i0; a1 = i1; }
        }
        for (int tb = 1; tb < mid; tb += U_) {
            #pragma unroll
            for (int u = 0; u < U_; ++u) {
                const int t = tb + u;
                const int slot = (1 + u) & 7;
                const float eb = rb[slot] * LOG2E;
                const float e1 = r1[slot] * LOG2E;
                const float e3 = r3[slot] * LOG2E;
                const int rr = t + U_;
                const int rc = rr < mid ? rr : last;
                const size_t o = (size_t)rc * rstride;
                const float nrb = pB[o], nr1 = p1[o], nr3 = p3[o];
                if (t < mid) {
                    const float sm1 = dppf<0x138>(NEGC, a3);   // lane l-1's a3
                    const float M = fmaxf(fmaxf(fmaxf(a0, a1), fmaxf(a2, a3)),
                                          fmaxf(a4, sm1));
                    const float q0 = exp2a(a0 - M);
                    const float q1 = exp2a(a1 - M);
                    const float q2 = exp2a(a2 - M);
                    const float q3 = exp2a(a3 - M);
                    const float q4 = exp2a(a4 - M);
                    const float qs = exp2a(sm1 - M);
                    const float Mb = M + eb;
                    a0 = log2a(q0 + qs)                      + Mb;
                    a1 = log2a(q1 + q0 + (skip1 ? qs : 0.f)) + M + e1;
                    a2 = log2a(q2 + q1)                      + Mb;
                    a3 = log2a(q3 + q2 + (skip3 ? q1 : 0.f)) + M + e3;
                    a4 = log2a(q4 + q3)                      + Mb;     // s=256 (lane 63)
                }
                rb[slot] = nrb; r1[slot] = nr1; r3[slot] = nr3;
            }
        }
        ga[4 * l + 0] = a0; ga[4 * l + 1] = a1;
        ga[4 * l + 2] = a2; ga[4 * l + 3] = a3;
        if (l == 63) ga[256] = a4;
    } else {
        // ---------------- backward: gamma_mid ----------------
        const int fe = len - 1;
        #pragma unroll
        for (int u = 0; u < U_; ++u) {
            int rc = fe - 1 - u; if (rc < 0) rc = 0;
            const size_t o = (size_t)rc * rstride;
            rb[u] = pB[o]; r1[u] = p1[o]; r3[u] = p3[o];
        }
        const int tl = tlen[n];
        const int sA = 2 * tl, sB = 2 * tl - 1;
        float g0, g1, g2, g3, g4;
        {
            const size_t o = (size_t)fe * rstride;
            const float ebi = pB[o] * LOG2E;
            const float e1i = p1[o] * LOG2E;
            const float e3i = p3[o] * LOG2E;
            const int s0 = 4 * l;
            g0 = (s0     == sA)                 ? ebi : NEGC;
            g1 = (s0 + 1 == sA || s0 + 1 == sB) ? e1i : NEGC;
            g2 = (s0 + 2 == sA)                 ? ebi : NEGC;
            g3 = (s0 + 3 == sA || s0 + 3 == sB) ? e3i : NEGC;
            g4 = (l == 63 && 256 == sA)         ? ebi : NEGC;
        }
        for (int tb = fe - 1; tb >= mid; tb -= U_) {
            #pragma unroll
            for (int u = 0; u < U_; ++u) {
                const int t = tb - u;
                const int slot = ((fe - 1 - tb) + u) & 7;  // == u
                const float eb = rb[slot] * LOG2E;
                const float e1 = r1[slot] * LOG2E;
                const float e3 = r3[slot] * LOG2E;
                int rc = t - U_; if (rc < 0) rc = 0;
                const size_t o = (size_t)rc * rstride;
                const float nrb = pB[o], nr1 = p1[o], nr3 = p3[o];
                if (t >= mid) {
                    const float nx0 = dppf<0x130>(g4,   g0);   // lane l+1's g0; l63 -> g4 (s=256)
                    const float nx1 = dppf<0x130>(NEGC, g1);   // lane l+1's g1; l63 -> NEG
                    const float M = fmaxf(fmaxf(fmaxf(g0, g1), fmaxf(g2, g3)),
                                          fmaxf(nx0, nx1));
                    const float q0 = exp2a(g0 - M);
                    const float q1 = exp2a(g1 - M);
                    const float q2 = exp2a(g2 - M);
                    const float q3 = exp2a(g3 - M);
                    const float qx0 = exp2a(nx0 - M);
                    const float qx1 = exp2a(nx1 - M);
                    const float skb1q = (ext3 != ext1) ? q3 : 0.f;     // skip_ok[4l+3]
                    g0 = log2a(q0 + q1)                        + M + eb;
                    g1 = log2a(q1 + q2 + skb1q)                + M + e1;
                    g2 = log2a(q2 + q3)                        + M + eb;
                    g3 = log2a(q3 + qx0 + (skb3 ? qx1 : 0.f))  + M + e3;
                    g4 = g4 + eb;                                      // s=256: stay only
                }
                rb[slot] = nrb; r1[slot] = nr1; r3[slot] = nr3;
            }
        }
        gg[4 * l + 0] = g0; gg[4 * l + 1] = g1;
        gg[4 * l + 2] = g2; gg[4 * l + 3] = g3;
        if (l == 63) gg[256] = g4;
    }
}

// ---------------- combine: P = sum_s abar[s] * gamma_mid[s] ----------------
__global__ __launch_bounds__(64) void ctc_comb(
    const float* __restrict__ ws, const int* __restrict__ tgt,
    const int* __restrict__ ilen, const int* __restrict__ tlen,
    float* __restrict__ out, int N)
{
    const int n = blockIdx.x;
    const int l = threadIdx.x;
    const float* ga = ws + (size_t)n * WROW;
    const float* gg = ga + 260;

    int len = ilen[n];
    len = len < 1 ? 1 : (len > T_ ? T_ : len);
    const int tl = tlen[n];

    if (len == 1) {                      // degenerate: loss directly from alpha_0
        if (l == 0) {
            const float v1 = ga[2 * tl];
            const float v2 = (2 * tl >= 1) ? ga[2 * tl - 1] : NEGC;
            float loss = -lse2(v1, v2) * LN2;
            if (!(loss < 1e10f) || !isfinite(loss)) loss = 0.0f;
            out[n] = loss;
        }
        return;
    }

    const int* tn = tgt + n * S_;
    const int ext1 = tn[2 * l];
    const int ext3 = tn[2 * l + 1];
    const int prev = (l > 0) ? tn[2 * l - 1] : 0;
    const bool skip1 = (l > 0) && (ext1 != prev);
    const bool skip3 = (ext3 != ext1);

    const int s0 = 4 * l;
    const float Am1 = (l > 0) ? ga[s0 - 1] : NEGC;
    const float A0 = ga[s0], A1 = ga[s0 + 1], A2 = ga[s0 + 2], A3 = ga[s0 + 3];
    const float v0 = lse2(A0, Am1)                    + gg[s0];
    const float v1 = lse3(A1, A0, skip1 ? Am1 : NEGC) + gg[s0 + 1];
    const float v2 = lse2(A2, A1)                     + gg[s0 + 2];
    const float v3 = lse3(A3, A2, skip3 ? A1 : NEGC)  + gg[s0 + 3];
    const float v4 = (l == 63) ? (lse2(ga[256], A3) + gg[256]) : NEGC;

    float m = fmaxf(fmaxf(v0, v1), fmaxf(fmaxf(v2, v3), v4));
    float ssum = exp2a(v0 - m) + exp2a(v1 - m) + exp2a(v2 - m)
               + exp2a(v3 - m) + exp2a(v4 - m);
    float M = m;
    #pragma unroll
    for (int d = 1; d < 64; d <<= 1) M = fmaxf(M, __shfl_xor(M, d));
    float r = ssum * exp2a(m - M);
    #pragma unroll
    for (int d = 1; d < 64; d <<= 1) r += __shfl_xor(r, d);
    if (l == 0) {
        float loss = -LN2 * (M + log2a(r));
        if (!(loss < 1e10f) || !isfinite(loss)) loss = 0.0f;
        out[n] = loss;
    }
}

// ---------------- fallback: exact R8 fused kernel (proven, absmax 0.0) ----------------
__global__ __launch_bounds__(128) void ctc_fused(
    const float* __restrict__ lp, const int* __restrict__ tgt,
    const int* __restrict__ ilen, const int* __restrict__ tlen,
    float* __restrict__ out, int N)
{
    const int n    = blockIdx.x;
    const int wave = threadIdx.x >> 6;
    const int l    = threadIdx.x & 63;

    __shared__ float ga[2 * S_ + 1];
    __shared__ float gg[2 * S_ + 1];

    const int* tn = tgt + n * S_;
    const int ext1 = tn[2 * l];
    const int ext3 = tn[2 * l + 1];
    const int prev = (l > 0) ? tn[2 * l - 1] : 0;
    const bool skip1 = (l > 0) && (ext1 != prev);
    const bool skip3 = (ext3 != ext1);
    const bool skb1 = (tn[2 * l + 1] != tn[2 * l]);
    const bool skb3 = (l < 63) && (tn[2 * l + 2] != tn[2 * l + 1]);

    int len = ilen[n];
    len = len < 1 ? 1 : (len > T_ ? T_ : len);
    const int mid = len >> 1;

    const size_t rstride = (size_t)N * C_;
    const float* lpn = lp + (size_t)n * C_;
    const float* pB = lpn;
    const float* p1 = lpn + ext1;
    const float* p3 = lpn + ext3;

    float rb[U_], r1[U_], r3[U_];

    if (wave == 0) {
        const int last = mid - 1 > 0 ? mid - 1 : 0;
        #pragma unroll
        for (int u = 0; u < U_; ++u) {
            const int r = u + 1;
            const int rc = r < mid ? r : last;
            const size_t o = (size_t)rc * rstride;
            rb[r & 7] = pB[o]; r1[r & 7] = p1[o]; r3[r & 7] = p3[o];
        }
        float a0 = NEGC, a1 = NEGC, a2 = NEGC, a3 = NEGC, a4 = NEGC;
        {
            const float i0 = pB[0] * LOG2E;
            const float i1 = p1[0] * LOG2E;
            if (l == 0) { a0 = i0; a1 = i1; }
        }
        for (int tb = 1; tb < mid; tb += U_) {
            #pragma unroll
            for (int u = 0; u < U_; ++u) {
                const int t = tb + u;
                const int slot = (1 + u) & 7;
                const float eb = rb[slot] * LOG2E;
                const float e1 = r1[slot] * LOG2E;
                const float e3 = r3[slot] * LOG2E;
                const int rr = t + U_;
                const int rc = rr < mid ? rr : last;
                const size_t o = (size_t)rc * rstride;
                const float nrb = pB[o], nr1 = p1[o], nr3 = p3[o];
                if (t < mid) {
                    const float sm1 = dppf<0x138>(NEGC, a3);
                    const float z1 = skip1 ? sm1 : NEGC;
                    const float z3 = skip3 ? a1  : NEGC;
                    const float n0 = lse2(a0, sm1)    + eb;
                    const float n1 = lse3(a1, a0, z1) + e1;
                    const float n2 = lse2(a2, a1)     + eb;
                    const float n3 = lse3(a3, a2, z3) + e3;
                    const float n4 = lse2(a4, a3)     + eb;
                    a0 = n0; a1 = n1; a2 = n2; a3 = n3; a4 = n4;
                }
                rb[slot] = nrb; r1[slot] = nr1; r3[slot] = nr3;
            }
        }
        ga[4 * l + 0] = a0; ga[4 * l + 1] = a1;
        ga[4 * l + 2] = a2; ga[4 * l + 3] = a3;
        if (l == 63) ga[256] = a4;
    } else {
        const int fe = len - 1;
        #pragma unroll
        for (int u = 0; u < U_; ++u) {
            int rc = fe - 1 - u; if (rc < 0) rc = 0;
            const size_t o = (size_t)rc * rstride;
            rb[u] = pB[o]; r1[u] = p1[o]; r3[u] = p3[o];
        }
        const int tl = tlen[n];
        const int sA = 2 * tl, sB = 2 * tl - 1;
        float g0, g1, g2, g3, g4;
        {
            const size_t o = (size_t)fe * rstride;
            const float ebi = pB[o] * LOG2E;
            const float e1i = p1[o] * LOG2E;
            const float e3i = p3[o] * LOG2E;
            const int s0 = 4 * l;
            g0 = (s0     == sA)                 ? ebi : NEGC;
            g1 = (s0 + 1 == sA || s0 + 1 == sB) ? e1i : NEGC;
            g2 = (s0 + 2 == sA)                 ? ebi : NEGC;
            g3 = (s0 + 3 == sA || s0 + 3 == sB) ? e3i : NEGC;
            g4 = (l == 63 && 256 == sA)         ? ebi : NEGC;
        }
        for (int tb = fe - 1; tb >= mid; tb -= U_) {
            #pragma unroll
            for (int u = 0; u < U_; ++u) {
                const int t = tb - u;
                const int slot = ((fe - 1 - tb) + u) & 7;
                const float eb = rb[slot] * LOG2E;
                const float e1 = r1[slot] * LOG2E;
                const float e3 = r3[slot] * LOG2E;
                int rc = t - U_; if (rc < 0) rc = 0;
                const size_t o = (size_t)rc * rstride;
                const float nrb = pB[o], nr1 = p1[o], nr3 = p3[o];
                if (t >= mid) {
                    const float nx0 = dppf<0x130>(g4,   g0);
                    const float nx1 = dppf<0x130>(NEGC, g1);
                    const float z1 = skb1 ? g3  : NEGC;
                    const float z3 = skb3 ? nx1 : NEGC;
                    const float n0 = lse2(g0, g1)      + eb;
                    const float n1 = lse3(g1, g2, z1)  + e1;
                    const float n2 = lse2(g2, g3)      + eb;
                    const float n3 = lse3(g3, nx0, z3) + e3;
                    const float n4 = g4 + eb;
                    g0 = n0; g1 = n1; g2 = n2; g3 = n3; g4 = n4;
                }
                rb[slot] = nrb; r1[slot] = nr1; r3[slot] = nr3;
            }
        }
        gg[4 * l + 0] = g0; gg[4 * l + 1] = g1;
        gg[4 * l + 2] = g2; gg[4 * l + 3] = g3;
        if (l == 63) gg[256] = g4;
    }

    __syncthreads();

    if (wave == 0) {
        const int tl = tlen[n];
        if (len == 1) {
            if (l == 0) {
                const float v1 = ga[2 * tl];
                const float v2 = (2 * tl >= 1) ? ga[2 * tl - 1] : NEGC;
                float loss = -lse2(v1, v2) * LN2;
                if (!(loss < 1e10f) || !isfinite(loss)) loss = 0.0f;
                out[n] = loss;
            }
            return;
        }
        const int s0 = 4 * l;
        const float Am1 = (l > 0) ? ga[s0 - 1] : NEGC;
        const float A0 = ga[s0], A1 = ga[s0 + 1], A2 = ga[s0 + 2], A3 = ga[s0 + 3];
        const float v0 = lse2(A0, Am1)                    + gg[s0];
        const float v1 = lse3(A1, A0, skip1 ? Am1 : NEGC) + gg[s0 + 1];
        const float v2 = lse2(A2, A1)                     + gg[s0 + 2];
        const float v3 = lse3(A3, A2, skip3 ? A1 : NEGC)  + gg[s0 + 3];
        const float v4 = (l == 63) ? (lse2(ga[256], A3) + gg[256]) : NEGC;

        float m = fmaxf(fmaxf(v0, v1), fmaxf(fmaxf(v2, v3), v4));
        float ssum = exp2a(v0 - m) + exp2a(v1 - m) + exp2a(v2 - m)
                   + exp2a(v3 - m) + exp2a(v4 - m);
        float M = m;
        #pragma unroll
        for (int d = 1; d < 64; d <<= 1) M = fmaxf(M, __shfl_xor(M, d));
        float r = ssum * exp2a(m - M);
        #pragma unroll
        for (int d = 1; d < 64; d <<= 1) r += __shfl_xor(r, d);
        if (l == 0) {
            float loss = -LN2 * (M + log2a(r));
            if (!(loss < 1e10f) || !isfinite(loss)) loss = 0.0f;
            out[n] = loss;
        }
    }
}

extern "C" void kernel_launch(void* const* d_in, const int* in_sizes, int n_in,
                              void* d_out, int out_size, void* d_ws, size_t ws_size,
                              hipStream_t stream) {
    const float* lp  = (const float*)d_in[0];
    const int*   tg  = (const int*)  d_in[1];
    const int*   il  = (const int*)  d_in[2];
    const int*   tl  = (const int*)  d_in[3];
    float*       out = (float*)d_out;
    const int N = in_sizes[2];  // 512
    const size_t need = (size_t)N * WROW * sizeof(float);  // ~1.06 MB
    if (ws_size >= need) {
        ctc_half<<<2 * N, 64, 0, stream>>>(lp, tg, il, tl, (float*)d_ws, N);
        ctc_comb<<<N, 64, 0, stream>>>((const float*)d_ws, tg, il, tl, out, N);
    } else {
        ctc_fused<<<N, 128, 0, stream>>>(lp, tg, il, tl, out, N);  // proven R8 path
    }
}